// Round 6
// baseline (573.337 us; speedup 1.0000x reference)
//
#include <hip/hip_runtime.h>
#include <hip/hip_bf16.h>

#define KK 5
constexpr int N0 = 78400;     // B*28*28
constexpr int E0 = 627200;    // N0*8
constexpr int N1 = 19600;     // B*14*14
constexpr int E1 = 156800;    // N1*8
constexpr int C1 = 32, C2 = 64;
constexpr int BSZ = 100;
constexpr int FC1_IN = 3136, FC1_OUT = 512;
constexpr int CAP = 48;       // max stored edges per node (Poisson(8) tail ~1e-20)

__device__ __forceinline__ void taps_of(const float* pseudo, int e,
                                        int& a00, int& a01, int& a10, int& a11,
                                        float& c00, float& c01, float& c10, float& c11) {
    float px = pseudo[2 * e] * (KK - 1);
    float py = pseudo[2 * e + 1] * (KK - 1);
    float kfx = floorf(px), kfy = floorf(py);
    float fx = px - kfx, fy = py - kfy;
    int k0x = min(max((int)kfx, 0), KK - 1);
    int k0y = min(max((int)kfy, 0), KK - 1);
    int k1x = min(k0x + 1, KK - 1), k1y = min(k0y + 1, KK - 1);
    a00 = k0x * KK + k0y; a01 = k0x * KK + k1y;
    a10 = k1x * KK + k0y; a11 = k1x * KK + k1y;
    float gx = 1.f - fx, gy = 1.f - fy;
    c00 = gx * gy; c01 = gx * fy; c10 = fx * gy; c11 = fx * fy;
}

// ---- bucket: one int atomic per edge; store edge id in dst's slot list ----
__global__ void bucket_edges(const int* __restrict__ ei, int nedges,
                             int* __restrict__ cnt, int* __restrict__ rec) {
    int e = blockIdx.x * blockDim.x + threadIdx.x;
    if (e >= nedges) return;
    int dstn = ei[nedges + e];
    int r = atomicAdd(&cnt[dstn], 1);
    if (r < CAP) rec[dstn * CAP + r] = e;
}

// ---- conv1 gather + node1 fused: thread (n, o). No atomics. ----
__global__ void gather1(const float* __restrict__ x, const float* __restrict__ ps0,
                        const int* __restrict__ ei0, const int* __restrict__ cnt1,
                        const int* __restrict__ rec1, const float* __restrict__ W1,
                        const float* __restrict__ root, const float* __restrict__ bias,
                        float* __restrict__ h1) {
    int idx = blockIdx.x * blockDim.x + threadIdx.x;
    if (idx >= N0 * C1) return;
    int n = idx >> 5, o = idx & 31;
    int cnt = cnt1[n];
    int m = min(cnt, CAP);
    const int* rp = rec1 + n * CAP;
    float acc = 0.f;
    for (int r = 0; r < m; r++) {
        int e = rp[r];
        int srcn = ei0[e];
        int a00, a01, a10, a11; float c00, c01, c10, c11;
        taps_of(ps0, e, a00, a01, a10, a11, c00, c01, c10, c11);
        float w = c00 * W1[a00 * C1 + o] + c01 * W1[a01 * C1 + o] +
                  c10 * W1[a10 * C1 + o] + c11 * W1[a11 * C1 + o];
        acc += x[srcn] * w;
    }
    float v = acc / fmaxf((float)cnt, 1.f) + x[n] * root[o] + bias[o];
    h1[idx] = v > 0.f ? v : expm1f(v);
}

// ---- pool1: [100,28,28,32] -> [100,14,14,32] ----
__global__ void pool1(const float* __restrict__ h1, float* __restrict__ p1) {
    int idx = blockIdx.x * blockDim.x + threadIdx.x;
    if (idx >= N1 * C1) return;
    int o = idx & 31; int t = idx >> 5;
    int c = t % 14; int r = (t / 14) % 14; int b = t / 196;
    const float* base = h1 + (((b * 28 + 2 * r) * 28 + 2 * c) * C1 + o);
    float m = fmaxf(fmaxf(base[0], base[C1]),
                    fmaxf(base[28 * C1], base[28 * C1 + C1]));
    p1[idx] = m;
}

// ---- build U[n, tap, i] = sum_{edges->n} c_tap * p1[src, i]; per-thread LDS accum ----
__global__ void build_U(const float* __restrict__ p1, const float* __restrict__ ps1,
                        const int* __restrict__ ei1, const int* __restrict__ cnt2,
                        const int* __restrict__ rec2, float* __restrict__ U) {
    __shared__ float Ul[256 * 25];   // 25.6 KB, private per thread
    int t = threadIdx.x;
    int i = t & 31;
    int nl = t >> 5;                 // 0..7
    int n = blockIdx.x * 8 + nl;
    float* up = Ul + t * 25;
#pragma unroll
    for (int a = 0; a < 25; a++) up[a] = 0.f;
    int m = min(cnt2[n], CAP);
    const int* rp = rec2 + n * CAP;
    for (int r = 0; r < m; r++) {
        int e = rp[r];
        int srcn = ei1[e];
        int a00, a01, a10, a11; float c00, c01, c10, c11;
        taps_of(ps1, e, a00, a01, a10, a11, c00, c01, c10, c11);
        float xv = p1[srcn * C1 + i];
        up[a00] += c00 * xv; up[a01] += c01 * xv;
        up[a10] += c10 * xv; up[a11] += c11 * xv;
    }
    float* Un = U + n * 800;
#pragma unroll
    for (int a = 0; a < 25; a++) Un[a * 32 + i] = up[a];
}

// ---- h2 = ELU( (U @ W2flat)/deg + p1 @ root2 + b2 ).  [19600,800]@[800,64] ----
// block: 64 nodes x 64 o; thread: 4 rows x 4 o (t = 16 ocol x 16 rgrp)
__global__ void gemm_h2(const float* __restrict__ U, const float* __restrict__ W2,
                        const float* __restrict__ p1, const float* __restrict__ root2,
                        const float* __restrict__ b2, const int* __restrict__ cnt2,
                        float* __restrict__ h2) {
    __shared__ float us[64 * 33];
    int t = threadIdx.x;
    int ocol = t & 15;               // *4 -> o base
    int rgrp = t >> 4;               // *4 -> row base
    int n0 = blockIdx.x * 64;
    float acc[4][4];
#pragma unroll
    for (int r = 0; r < 4; r++)
#pragma unroll
        for (int c = 0; c < 4; c++) acc[r][c] = 0.f;

    int lrow = t >> 5, lkk = t & 31;
    for (int kc = 0; kc < 800; kc += 32) {
        __syncthreads();
        for (int rr = 0; rr < 64; rr += 8) {
            int row = rr + lrow;
            int n = n0 + row;
            us[row * 33 + lkk] = (n < N1) ? U[n * 800 + kc + lkk] : 0.f;
        }
        __syncthreads();
        for (int k = 0; k < 32; k++) {
            const float4 w4 = *(const float4*)&W2[(kc + k) * 64 + ocol * 4];
            float xr[4];
#pragma unroll
            for (int r = 0; r < 4; r++) xr[r] = us[(rgrp * 4 + r) * 33 + k];
#pragma unroll
            for (int r = 0; r < 4; r++) {
                acc[r][0] += xr[r] * w4.x; acc[r][1] += xr[r] * w4.y;
                acc[r][2] += xr[r] * w4.z; acc[r][3] += xr[r] * w4.w;
            }
        }
    }
    // root term: stage p1 tile [64 x 32] (ALL 64 rows) then rank-32 update
    __syncthreads();
    for (int rr = 0; rr < 64; rr += 8) {
        int row = rr + lrow;
        int n = n0 + row;
        us[row * 33 + lkk] = (n < N1) ? p1[n * C1 + lkk] : 0.f;
    }
    __syncthreads();
    float racc[4][4];
#pragma unroll
    for (int r = 0; r < 4; r++)
#pragma unroll
        for (int c = 0; c < 4; c++) racc[r][c] = 0.f;
    for (int i = 0; i < 32; i++) {
        const float4 w4 = *(const float4*)&root2[i * 64 + ocol * 4];
#pragma unroll
        for (int r = 0; r < 4; r++) {
            float xv = us[(rgrp * 4 + r) * 33 + i];
            racc[r][0] += xv * w4.x; racc[r][1] += xv * w4.y;
            racc[r][2] += xv * w4.z; racc[r][3] += xv * w4.w;
        }
    }
    const float4 bb = *(const float4*)&b2[ocol * 4];
#pragma unroll
    for (int r = 0; r < 4; r++) {
        int n = n0 + rgrp * 4 + r;
        if (n >= N1) continue;
        float invd = 1.f / fmaxf((float)cnt2[n], 1.f);
        float4 v;
        v.x = acc[r][0] * invd + racc[r][0] + bb.x;
        v.y = acc[r][1] * invd + racc[r][1] + bb.y;
        v.z = acc[r][2] * invd + racc[r][2] + bb.z;
        v.w = acc[r][3] * invd + racc[r][3] + bb.w;
        v.x = v.x > 0.f ? v.x : expm1f(v.x);
        v.y = v.y > 0.f ? v.y : expm1f(v.y);
        v.z = v.z > 0.f ? v.z : expm1f(v.z);
        v.w = v.w > 0.f ? v.w : expm1f(v.w);
        *(float4*)&h2[n * 64 + ocol * 4] = v;
    }
}

// ---- pool2: view [19600,64] as [25,28,28,64] -> [25,14,14,64] == [100,3136] ----
__global__ void pool2(const float* __restrict__ h2, float* __restrict__ p2) {
    int idx = blockIdx.x * blockDim.x + threadIdx.x;
    if (idx >= 25 * 14 * 14 * C2) return;
    int o = idx & 63; int t = idx >> 6;
    int c = t % 14; int r = (t / 14) % 14; int b = t / 196;
    const float* base = h2 + (((b * 28 + 2 * r) * 28 + 2 * c) * C2 + o);
    float m = fmaxf(fmaxf(base[0], base[C2]),
                    fmaxf(base[28 * C2], base[28 * C2 + C2]));
    p2[idx] = m;
}

// ---- fc1 partials: grid (8 jt, 16 kz), block 256 (64 j x 4 bgroups of 25).
// x-tile [100 x 196] in LDS shared by all j; w read exactly once overall.
__global__ void fc1_part(const float* __restrict__ p2, const float* __restrict__ w,
                         float* __restrict__ z1p) {
    __shared__ float xs[100 * 196];  // 78.4 KB
    int t = threadIdx.x;
    int jt = blockIdx.x, kz = blockIdx.y;
    int j = (jt << 6) + (t & 63);
    int bg = t >> 6;                 // 0..3 -> rows bg*25..bg*25+24
    int k0 = kz * 196;
    for (int i = t; i < 100 * 196; i += 256) {
        int b = i / 196, kk = i - b * 196;
        xs[i] = p2[b * FC1_IN + k0 + kk];
    }
    __syncthreads();
    float acc[25];
#pragma unroll
    for (int b = 0; b < 25; b++) acc[b] = 0.f;
    const float* wp = w + j;
    for (int k = 0; k < 196; k += 4) {
        float w0 = wp[(k0 + k) * FC1_OUT];
        float w1 = wp[(k0 + k + 1) * FC1_OUT];
        float w2 = wp[(k0 + k + 2) * FC1_OUT];
        float w3 = wp[(k0 + k + 3) * FC1_OUT];
#pragma unroll
        for (int b = 0; b < 25; b++) {
            const float4 xv = *(const float4*)&xs[(bg * 25 + b) * 196 + k];
            acc[b] += xv.x * w0 + xv.y * w1 + xv.z * w2 + xv.w * w3;
        }
    }
#pragma unroll
    for (int b = 0; b < 25; b++)
        z1p[kz * (BSZ * FC1_OUT) + (bg * 25 + b) * FC1_OUT + j] = acc[b];
}

// ---- fc2 + log_softmax fused; sums 16 fc1 partials, applies fc1 bias+ELU ----
__global__ void fc2_lsm(const float* __restrict__ z1p, const float* __restrict__ fc1b,
                        const float* __restrict__ w, const float* __restrict__ fc2b,
                        float* __restrict__ out) {
    int b = blockIdx.x;
    int t = threadIdx.x;
    int wv = t >> 6;
    int lane = t & 63;
    float acc = 0.f;
#pragma unroll
    for (int m = 0; m < 8; m++) {
        int k = lane * 8 + m;
        float xv = fc1b[k];
        for (int kz = 0; kz < 16; kz++) xv += z1p[kz * (BSZ * FC1_OUT) + b * FC1_OUT + k];
        xv = xv > 0.f ? xv : expm1f(xv);
        acc += xv * w[k * 10 + wv];
    }
#pragma unroll
    for (int off = 32; off > 0; off >>= 1) acc += __shfl_down(acc, off);
    __shared__ float zs[10];
    if (lane == 0) {
        float z = acc + fc2b[wv];
        zs[wv] = z > 0.f ? z : expm1f(z);
    }
    __syncthreads();
    if (t < 10) {
        float m = -1e30f;
        for (int jj = 0; jj < 10; jj++) m = fmaxf(m, zs[jj]);
        float s = 0.f;
        for (int jj = 0; jj < 10; jj++) s += expf(zs[jj] - m);
        out[b * 10 + t] = zs[t] - m - logf(s);
    }
}

extern "C" void kernel_launch(void* const* d_in, const int* in_sizes, int n_in,
                              void* d_out, int out_size, void* d_ws, size_t ws_size,
                              hipStream_t stream) {
    const float* x     = (const float*)d_in[0];
    const float* ps0   = (const float*)d_in[1];
    const float* ps1   = (const float*)d_in[2];
    const float* W1    = (const float*)d_in[3];
    const float* root1 = (const float*)d_in[4];
    const float* b1    = (const float*)d_in[5];
    const float* W2    = (const float*)d_in[6];
    const float* root2 = (const float*)d_in[7];
    const float* b2v   = (const float*)d_in[8];
    const float* fc1w  = (const float*)d_in[9];
    const float* fc1b  = (const float*)d_in[10];
    const float* fc2w  = (const float*)d_in[11];
    const float* fc2b  = (const float*)d_in[12];
    const int*   ei0   = (const int*)d_in[13];
    const int*   ei1   = (const int*)d_in[14];

    float* ws = (float*)d_ws;
    int*   cnt1 = (int*)ws;                        //      78,400
    int*   cnt2 = (int*)(ws + 78400);              //      19,600
    // ---- memset boundary: 98,000 words ----
    int*   rec1 = (int*)(ws + 98000);              //   3,763,200 (N0*CAP)
    int*   rec2 = (int*)(ws + 3861200);            //     940,800 (N1*CAP)
    float* h1   = ws + 4802000;                    //   2,508,800
    float* p1   = ws + 7310800;                    //     627,200
    float* U    = ws + 7938000;                    //  15,680,000
    float* h2   = ws + 23618000;                   //   1,254,400
    float* p2   = ws + 24872400;                   //     313,600
    float* z1p  = ws + 25186000;                   //     819,200
    // high water: 26,005,200 words = 104.0 MB

    hipMemsetAsync(ws, 0, (size_t)98000 * sizeof(float), stream);

    bucket_edges<<<(E0 + 255) / 256, 256, 0, stream>>>(ei0, E0, cnt1, rec1);
    bucket_edges<<<(E1 + 255) / 256, 256, 0, stream>>>(ei1, E1, cnt2, rec2);
    gather1<<<(N0 * C1 + 255) / 256, 256, 0, stream>>>(x, ps0, ei0, cnt1, rec1,
                                                       W1, root1, b1, h1);
    pool1<<<(N1 * C1 + 255) / 256, 256, 0, stream>>>(h1, p1);
    build_U<<<N1 / 8, 256, 0, stream>>>(p1, ps1, ei1, cnt2, rec2, U);
    gemm_h2<<<(N1 + 63) / 64, 256, 0, stream>>>(U, W2, p1, root2, b2v, cnt2, h2);
    pool2<<<(25 * 14 * 14 * C2 + 255) / 256, 256, 0, stream>>>(h2, p2);
    fc1_part<<<dim3(8, 16), 256, 0, stream>>>(p2, fc1w, z1p);
    fc2_lsm<<<BSZ, 640, 0, stream>>>(z1p, fc1b, fc2w, fc2b, (float*)d_out);
}

// Round 7
// 423.797 us; speedup vs baseline: 1.3529x; 1.3529x over previous
//
#include <hip/hip_runtime.h>
#include <hip/hip_bf16.h>

#define KK 5
constexpr int N0 = 78400;     // B*28*28
constexpr int E0 = 627200;    // N0*8
constexpr int N1 = 19600;     // B*14*14
constexpr int E1 = 156800;    // N1*8
constexpr int C1 = 32, C2 = 64;
constexpr int BSZ = 100;
constexpr int FC1_IN = 3136, FC1_OUT = 512;
constexpr int CAP = 48;       // max stored edges per node (Poisson(8) tail ~1e-20)

__device__ __forceinline__ void taps_of(const float* pseudo, int e,
                                        int& a00, int& a01, int& a10, int& a11,
                                        float& c00, float& c01, float& c10, float& c11) {
    float px = pseudo[2 * e] * (KK - 1);
    float py = pseudo[2 * e + 1] * (KK - 1);
    float kfx = floorf(px), kfy = floorf(py);
    float fx = px - kfx, fy = py - kfy;
    int k0x = min(max((int)kfx, 0), KK - 1);
    int k0y = min(max((int)kfy, 0), KK - 1);
    int k1x = min(k0x + 1, KK - 1), k1y = min(k0y + 1, KK - 1);
    a00 = k0x * KK + k0y; a01 = k0x * KK + k1y;
    a10 = k1x * KK + k0y; a11 = k1x * KK + k1y;
    float gx = 1.f - fx, gy = 1.f - fy;
    c00 = gx * gy; c01 = gx * fy; c10 = fx * gy; c11 = fx * fy;
}

// ---- bucket: one int atomic per edge; store edge id in dst's slot list ----
__global__ void bucket_edges(const int* __restrict__ ei, int nedges,
                             int* __restrict__ cnt, int* __restrict__ rec) {
    int e = blockIdx.x * blockDim.x + threadIdx.x;
    if (e >= nedges) return;
    int dstn = ei[nedges + e];
    int r = atomicAdd(&cnt[dstn], 1);
    if (r < CAP) rec[dstn * CAP + r] = e;
}

// ---- conv1 fused: 64 nodes/block. Phase1: tap-space S in LDS (4 thr/node).
//      Phase2: h1[n,o] = ELU((S@W1)/deg + x*root + bias). No atomics. ----
__global__ void conv1_fused(const float* __restrict__ x, const float* __restrict__ ps0,
                            const int* __restrict__ ei0, const int* __restrict__ cnt1,
                            const int* __restrict__ rec1, const float* __restrict__ W1,
                            const float* __restrict__ root, const float* __restrict__ bias,
                            float* __restrict__ h1) {
    __shared__ float S4[64][4][25];   // 25.6 KB, thread-private quadrants
    __shared__ float Sr[64][25];      // 6.4 KB, reduced
    int t = threadIdx.x;
    int nb = blockIdx.x * 64;
    {
        int q = t & 3, nl = t >> 2;
        float* sp = &S4[nl][q][0];
#pragma unroll
        for (int a = 0; a < 25; a++) sp[a] = 0.f;
        int m = min(cnt1[nb + nl], CAP);
        const int* rp = rec1 + (nb + nl) * CAP;
        for (int r = q; r < m; r += 4) {
            int e = rp[r];
            int srcn = ei0[e];
            int a00, a01, a10, a11; float c00, c01, c10, c11;
            taps_of(ps0, e, a00, a01, a10, a11, c00, c01, c10, c11);
            float xv = x[srcn];
            sp[a00] += c00 * xv; sp[a01] += c01 * xv;
            sp[a10] += c10 * xv; sp[a11] += c11 * xv;
        }
    }
    __syncthreads();
    // reduce quadrants: 1600 slots / 256 threads
    for (int idx = t; idx < 64 * 25; idx += 256) {
        int nl = idx / 25, a = idx - nl * 25;
        Sr[nl][a] = S4[nl][0][a] + S4[nl][1][a] + S4[nl][2][a] + S4[nl][3][a];
    }
    __syncthreads();
    // phase 2: o = t&31, ng = t>>5; nodes ng*8..ng*8+7
    int o = t & 31, ng = t >> 5;
    float w1c[25];
#pragma unroll
    for (int a = 0; a < 25; a++) w1c[a] = W1[a * C1 + o];
    float ro = root[o], bo = bias[o];
    for (int j = 0; j < 8; j++) {
        int nl = ng * 8 + j;
        int n = nb + nl;
        float acc = 0.f;
#pragma unroll
        for (int a = 0; a < 25; a++) acc += Sr[nl][a] * w1c[a];
        float v = acc / fmaxf((float)cnt1[n], 1.f) + x[n] * ro + bo;
        h1[n * C1 + o] = v > 0.f ? v : expm1f(v);
    }
}

// ---- pool1: [100,28,28,32] -> [100,14,14,32] ----
__global__ void pool1(const float* __restrict__ h1, float* __restrict__ p1) {
    int idx = blockIdx.x * blockDim.x + threadIdx.x;
    if (idx >= N1 * C1) return;
    int o = idx & 31; int t = idx >> 5;
    int c = t % 14; int r = (t / 14) % 14; int b = t / 196;
    const float* base = h1 + (((b * 28 + 2 * r) * 28 + 2 * c) * C1 + o);
    float m = fmaxf(fmaxf(base[0], base[C1]),
                    fmaxf(base[28 * C1], base[28 * C1 + C1]));
    p1[idx] = m;
}

// ---- conv2 fused: 16 nodes/block. Phase1: U[16][800] in LDS (tap-space,
//      2 nodes per 32-thread channel group). Phase2: h2 = ELU((U@W2)/deg +
//      p1@root2 + b2) with W2 tile staged in LDS. U never touches HBM. ----
__global__ void conv2_fused(const float* __restrict__ p1, const float* __restrict__ ps1,
                            const int* __restrict__ ei1, const int* __restrict__ cnt2,
                            const int* __restrict__ rec2, const float* __restrict__ W2,
                            const float* __restrict__ root2, const float* __restrict__ b2,
                            float* __restrict__ h2) {
    __shared__ float Ul[16][800];     // 51.2 KB
    __shared__ float pl[16][32];      // 2 KB
    __shared__ float w2l[32][64];     // 8 KB
    int t = threadIdx.x;
    int nb = blockIdx.x * 16;
    {
        int i = t & 31, nl = t >> 5;  // nl 0..7; handles nodes nl, nl+8
        for (int nn = nl; nn < 16; nn += 8) {
            int n = nb + nn;
            float* up = &Ul[nn][0];
#pragma unroll
            for (int a = 0; a < 25; a++) up[a * 32 + i] = 0.f;
            pl[nn][i] = p1[n * C1 + i];
            int m = min(cnt2[n], CAP);
            const int* rp = rec2 + n * CAP;
            for (int r = 0; r < m; r++) {
                int e = rp[r];
                int srcn = ei1[e];
                int a00, a01, a10, a11; float c00, c01, c10, c11;
                taps_of(ps1, e, a00, a01, a10, a11, c00, c01, c10, c11);
                float xv = p1[srcn * C1 + i];
                up[a00 * 32 + i] += c00 * xv; up[a01 * 32 + i] += c01 * xv;
                up[a10 * 32 + i] += c10 * xv; up[a11 * 32 + i] += c11 * xv;
            }
        }
    }
    // phase 2: o = t&63, ng = t>>6 (0..3); nodes ng, ng+4, ng+8, ng+12
    int o = t & 63, ng = t >> 6;
    float acc[4] = {0.f, 0.f, 0.f, 0.f};
    for (int kc = 0; kc < 800; kc += 32) {
        __syncthreads();              // first iter: phase1 barrier; later: w2l reuse
        for (int idx = t; idx < 32 * 64; idx += 256)
            w2l[idx >> 6][idx & 63] = W2[(kc + (idx >> 6)) * 64 + (idx & 63)];
        __syncthreads();
#pragma unroll 8
        for (int k = 0; k < 32; k++) {
            float wv = w2l[k][o];
            acc[0] += Ul[ng][kc + k] * wv;
            acc[1] += Ul[ng + 4][kc + k] * wv;
            acc[2] += Ul[ng + 8][kc + k] * wv;
            acc[3] += Ul[ng + 12][kc + k] * wv;
        }
    }
    float racc[4] = {0.f, 0.f, 0.f, 0.f};
#pragma unroll 8
    for (int i2 = 0; i2 < 32; i2++) {
        float wv = root2[i2 * 64 + o];
        racc[0] += pl[ng][i2] * wv;      racc[1] += pl[ng + 4][i2] * wv;
        racc[2] += pl[ng + 8][i2] * wv;  racc[3] += pl[ng + 12][i2] * wv;
    }
    float bo = b2[o];
#pragma unroll
    for (int q = 0; q < 4; q++) {
        int n = nb + ng + q * 4;
        float invd = 1.f / fmaxf((float)cnt2[n], 1.f);
        float v = acc[q] * invd + racc[q] + bo;
        h2[n * 64 + o] = v > 0.f ? v : expm1f(v);
    }
}

// ---- pool2: view [19600,64] as [25,28,28,64] -> [25,14,14,64] == [100,3136] ----
__global__ void pool2(const float* __restrict__ h2, float* __restrict__ p2) {
    int idx = blockIdx.x * blockDim.x + threadIdx.x;
    if (idx >= 25 * 14 * 14 * C2) return;
    int o = idx & 63; int t = idx >> 6;
    int c = t % 14; int r = (t / 14) % 14; int b = t / 196;
    const float* base = h2 + (((b * 28 + 2 * r) * 28 + 2 * c) * C2 + o);
    float m = fmaxf(fmaxf(base[0], base[C2]),
                    fmaxf(base[28 * C2], base[28 * C2 + C2]));
    p2[idx] = m;
}

// ---- fc1 partials: grid (8 jt, 16 kz), block 256 (64 j x 4 bgroups of 25).
// x-tile [100 x 196] in LDS shared by all j; w read exactly once overall.
__global__ void fc1_part(const float* __restrict__ p2, const float* __restrict__ w,
                         float* __restrict__ z1p) {
    __shared__ float xs[100 * 196];  // 78.4 KB
    int t = threadIdx.x;
    int jt = blockIdx.x, kz = blockIdx.y;
    int j = (jt << 6) + (t & 63);
    int bg = t >> 6;                 // 0..3 -> rows bg*25..bg*25+24
    int k0 = kz * 196;
    for (int i = t; i < 100 * 196; i += 256) {
        int b = i / 196, kk = i - b * 196;
        xs[i] = p2[b * FC1_IN + k0 + kk];
    }
    __syncthreads();
    float acc[25];
#pragma unroll
    for (int b = 0; b < 25; b++) acc[b] = 0.f;
    const float* wp = w + j;
    for (int k = 0; k < 196; k += 4) {
        float w0 = wp[(k0 + k) * FC1_OUT];
        float w1 = wp[(k0 + k + 1) * FC1_OUT];
        float w2 = wp[(k0 + k + 2) * FC1_OUT];
        float w3 = wp[(k0 + k + 3) * FC1_OUT];
#pragma unroll
        for (int b = 0; b < 25; b++) {
            const float4 xv = *(const float4*)&xs[(bg * 25 + b) * 196 + k];
            acc[b] += xv.x * w0 + xv.y * w1 + xv.z * w2 + xv.w * w3;
        }
    }
#pragma unroll
    for (int b = 0; b < 25; b++)
        z1p[kz * (BSZ * FC1_OUT) + (bg * 25 + b) * FC1_OUT + j] = acc[b];
}

// ---- fc2 + log_softmax fused; sums 16 fc1 partials, applies fc1 bias+ELU ----
__global__ void fc2_lsm(const float* __restrict__ z1p, const float* __restrict__ fc1b,
                        const float* __restrict__ w, const float* __restrict__ fc2b,
                        float* __restrict__ out) {
    int b = blockIdx.x;
    int t = threadIdx.x;
    int wv = t >> 6;
    int lane = t & 63;
    float acc = 0.f;
#pragma unroll
    for (int m = 0; m < 8; m++) {
        int k = lane * 8 + m;
        float xv = fc1b[k];
        for (int kz = 0; kz < 16; kz++) xv += z1p[kz * (BSZ * FC1_OUT) + b * FC1_OUT + k];
        xv = xv > 0.f ? xv : expm1f(xv);
        acc += xv * w[k * 10 + wv];
    }
#pragma unroll
    for (int off = 32; off > 0; off >>= 1) acc += __shfl_down(acc, off);
    __shared__ float zs[10];
    if (lane == 0) {
        float z = acc + fc2b[wv];
        zs[wv] = z > 0.f ? z : expm1f(z);
    }
    __syncthreads();
    if (t < 10) {
        float m = -1e30f;
        for (int jj = 0; jj < 10; jj++) m = fmaxf(m, zs[jj]);
        float s = 0.f;
        for (int jj = 0; jj < 10; jj++) s += expf(zs[jj] - m);
        out[b * 10 + t] = zs[t] - m - logf(s);
    }
}

extern "C" void kernel_launch(void* const* d_in, const int* in_sizes, int n_in,
                              void* d_out, int out_size, void* d_ws, size_t ws_size,
                              hipStream_t stream) {
    const float* x     = (const float*)d_in[0];
    const float* ps0   = (const float*)d_in[1];
    const float* ps1   = (const float*)d_in[2];
    const float* W1    = (const float*)d_in[3];
    const float* root1 = (const float*)d_in[4];
    const float* b1    = (const float*)d_in[5];
    const float* W2    = (const float*)d_in[6];
    const float* root2 = (const float*)d_in[7];
    const float* b2v   = (const float*)d_in[8];
    const float* fc1w  = (const float*)d_in[9];
    const float* fc1b  = (const float*)d_in[10];
    const float* fc2w  = (const float*)d_in[11];
    const float* fc2b  = (const float*)d_in[12];
    const int*   ei0   = (const int*)d_in[13];
    const int*   ei1   = (const int*)d_in[14];

    float* ws = (float*)d_ws;
    int*   cnt1 = (int*)ws;                        //      78,400
    int*   cnt2 = (int*)(ws + 78400);              //      19,600
    // ---- memset boundary: 98,000 words ----
    int*   rec1 = (int*)(ws + 98000);              //   3,763,200 (N0*CAP)
    int*   rec2 = (int*)(ws + 3861200);            //     940,800 (N1*CAP)
    float* h1   = ws + 4802000;                    //   2,508,800
    float* p1   = ws + 7310800;                    //     627,200
    float* h2   = ws + 7938000;                    //   1,254,400
    float* p2   = ws + 9192400;                    //     313,600
    float* z1p  = ws + 9506000;                    //     819,200
    // high water: 10,325,200 words = 41.3 MB

    hipMemsetAsync(ws, 0, (size_t)98000 * sizeof(float), stream);

    bucket_edges<<<(E0 + 255) / 256, 256, 0, stream>>>(ei0, E0, cnt1, rec1);
    bucket_edges<<<(E1 + 255) / 256, 256, 0, stream>>>(ei1, E1, cnt2, rec2);
    conv1_fused<<<N0 / 64, 256, 0, stream>>>(x, ps0, ei0, cnt1, rec1,
                                             W1, root1, b1, h1);
    pool1<<<(N1 * C1 + 255) / 256, 256, 0, stream>>>(h1, p1);
    conv2_fused<<<N1 / 16, 256, 0, stream>>>(p1, ps1, ei1, cnt2, rec2,
                                             W2, root2, b2v, h2);
    pool2<<<(25 * 14 * 14 * C2 + 255) / 256, 256, 0, stream>>>(h2, p2);
    fc1_part<<<dim3(8, 16), 256, 0, stream>>>(p2, fc1w, z1p);
    fc2_lsm<<<BSZ, 640, 0, stream>>>(z1p, fc1b, fc2w, fc2b, (float*)d_out);
}

// Round 8
// 324.177 us; speedup vs baseline: 1.7686x; 1.3073x over previous
//
#include <hip/hip_runtime.h>
#include <hip/hip_bf16.h>

#define KK 5
constexpr int N0 = 78400;     // B*28*28
constexpr int E0 = 627200;    // N0*8
constexpr int N1 = 19600;     // B*14*14
constexpr int E1 = 156800;    // N1*8
constexpr int C1 = 32, C2 = 64;
constexpr int BSZ = 100;
constexpr int FC1_IN = 3136, FC1_OUT = 512;
constexpr int CAP = 48;       // max stored edges per node (Poisson(8) tail ~1e-20)
constexpr int KEXT = 832;     // 800 tap-space + 32 root channels
constexpr int ULS = 832;      // LDS fp32 U row stride (floats)
constexpr int UBS = 856;      // LDS bf16 U row stride (ushorts); 856*2%16==0, bank-stagger 12

typedef __attribute__((ext_vector_type(8))) short bf16x8;
typedef __attribute__((ext_vector_type(4))) float f32x4;

__device__ __forceinline__ unsigned short f2bf(float f) {
    union { float f; unsigned u; } v; v.f = f;
    unsigned u = v.u;
    unsigned r = (u + 0x7FFF + ((u >> 16) & 1)) >> 16;   // RNE
    return (unsigned short)r;
}

__device__ __forceinline__ void taps_of(const float* pseudo, int e,
                                        int& a00, int& a01, int& a10, int& a11,
                                        float& c00, float& c01, float& c10, float& c11) {
    float px = pseudo[2 * e] * (KK - 1);
    float py = pseudo[2 * e + 1] * (KK - 1);
    float kfx = floorf(px), kfy = floorf(py);
    float fx = px - kfx, fy = py - kfy;
    int k0x = min(max((int)kfx, 0), KK - 1);
    int k0y = min(max((int)kfy, 0), KK - 1);
    int k1x = min(k0x + 1, KK - 1), k1y = min(k0y + 1, KK - 1);
    a00 = k0x * KK + k0y; a01 = k0x * KK + k1y;
    a10 = k1x * KK + k0y; a11 = k1x * KK + k1y;
    float gx = 1.f - fx, gy = 1.f - fy;
    c00 = gx * gy; c01 = gx * fy; c10 = fx * gy; c11 = fx * fy;
}

// ---- bucket: one int atomic per edge; store edge id in dst's slot list ----
__global__ void bucket_edges(const int* __restrict__ ei, int nedges,
                             int* __restrict__ cnt, int* __restrict__ rec) {
    int e = blockIdx.x * blockDim.x + threadIdx.x;
    if (e >= nedges) return;
    int dstn = ei[nedges + e];
    int r = atomicAdd(&cnt[dstn], 1);
    if (r < CAP) rec[dstn * CAP + r] = e;
}

// ---- conv1 fused: 64 nodes/block. Phase1: tap-space S in LDS (4 thr/node).
//      Phase2: h1[n,o] = ELU((S@W1)/deg + x*root + bias). No atomics. ----
__global__ void conv1_fused(const float* __restrict__ x, const float* __restrict__ ps0,
                            const int* __restrict__ ei0, const int* __restrict__ cnt1,
                            const int* __restrict__ rec1, const float* __restrict__ W1,
                            const float* __restrict__ root, const float* __restrict__ bias,
                            float* __restrict__ h1) {
    __shared__ float S4[64][4][25];   // 25.6 KB, thread-private quadrants
    __shared__ float Sr[64][25];      // 6.4 KB, reduced
    int t = threadIdx.x;
    int nb = blockIdx.x * 64;
    {
        int q = t & 3, nl = t >> 2;
        float* sp = &S4[nl][q][0];
#pragma unroll
        for (int a = 0; a < 25; a++) sp[a] = 0.f;
        int m = min(cnt1[nb + nl], CAP);
        const int* rp = rec1 + (nb + nl) * CAP;
        for (int r = q; r < m; r += 4) {
            int e = rp[r];
            int srcn = ei0[e];
            int a00, a01, a10, a11; float c00, c01, c10, c11;
            taps_of(ps0, e, a00, a01, a10, a11, c00, c01, c10, c11);
            float xv = x[srcn];
            sp[a00] += c00 * xv; sp[a01] += c01 * xv;
            sp[a10] += c10 * xv; sp[a11] += c11 * xv;
        }
    }
    __syncthreads();
    for (int idx = t; idx < 64 * 25; idx += 256) {
        int nl = idx / 25, a = idx - nl * 25;
        Sr[nl][a] = S4[nl][0][a] + S4[nl][1][a] + S4[nl][2][a] + S4[nl][3][a];
    }
    __syncthreads();
    int o = t & 31, ng = t >> 5;
    float w1c[25];
#pragma unroll
    for (int a = 0; a < 25; a++) w1c[a] = W1[a * C1 + o];
    float ro = root[o], bo = bias[o];
    for (int j = 0; j < 8; j++) {
        int nl = ng * 8 + j;
        int n = nb + nl;
        float acc = 0.f;
#pragma unroll
        for (int a = 0; a < 25; a++) acc += Sr[nl][a] * w1c[a];
        float v = acc / fmaxf((float)cnt1[n], 1.f) + x[n] * ro + bo;
        h1[n * C1 + o] = v > 0.f ? v : expm1f(v);
    }
}

// ---- pool1: [100,28,28,32] -> [100,14,14,32] ----
__global__ void pool1(const float* __restrict__ h1, float* __restrict__ p1) {
    int idx = blockIdx.x * blockDim.x + threadIdx.x;
    if (idx >= N1 * C1) return;
    int o = idx & 31; int t = idx >> 5;
    int c = t % 14; int r = (t / 14) % 14; int b = t / 196;
    const float* base = h1 + (((b * 28 + 2 * r) * 28 + 2 * c) * C1 + o);
    float m = fmaxf(fmaxf(base[0], base[C1]),
                    fmaxf(base[28 * C1], base[28 * C1 + C1]));
    p1[idx] = m;
}

// ---- w2t prep: bf16 transposed W2ext [64 o][832 k]; k<800 -> W2, else root2 ----
__global__ void w2t_prep(const float* __restrict__ W2, const float* __restrict__ root2,
                         unsigned short* __restrict__ w2t) {
    int idx = blockIdx.x * blockDim.x + threadIdx.x;
    if (idx >= 64 * KEXT) return;
    int o = idx / KEXT, k = idx - o * KEXT;
    float v = (k < 800) ? W2[k * 64 + o] : root2[(k - 800) * 64 + o];
    w2t[idx] = f2bf(v);
}

// ---- conv2 fused (MFMA): 16 nodes/block.
//  Phase1: U[16][832] fp32 in LDS (800 tap-space + 32 p1 channels).
//  Convert: bf16 with invd folded into the tap part.
//  Phase2: h2 = ELU( U_bf16 @ w2t^T + b2 ) via mfma_f32_16x16x32_bf16.
__global__ void conv2_fused(const float* __restrict__ p1, const float* __restrict__ ps1,
                            const int* __restrict__ ei1, const int* __restrict__ cnt2,
                            const int* __restrict__ rec2,
                            const unsigned short* __restrict__ w2t,
                            const float* __restrict__ b2, float* __restrict__ h2) {
    __shared__ float Ul[16 * ULS];          // 53.2 KB
    __shared__ unsigned short Ub[16 * UBS]; // 27.4 KB
    int t = threadIdx.x;
    int nb = blockIdx.x * 16;
    // phase 1: edge gather into fp32 tap-space
    {
        int i = t & 31, nl = t >> 5;
        for (int nn = nl; nn < 16; nn += 8) {
            int n = nb + nn;
            float* up = Ul + nn * ULS;
#pragma unroll
            for (int a = 0; a < 25; a++) up[a * 32 + i] = 0.f;
            up[800 + i] = p1[n * C1 + i];
            int m = min(cnt2[n], CAP);
            const int* rp = rec2 + n * CAP;
            for (int r = 0; r < m; r++) {
                int e = rp[r];
                int srcn = ei1[e];
                int a00, a01, a10, a11; float c00, c01, c10, c11;
                taps_of(ps1, e, a00, a01, a10, a11, c00, c01, c10, c11);
                float xv = p1[srcn * C1 + i];
                up[a00 * 32 + i] += c00 * xv; up[a01 * 32 + i] += c01 * xv;
                up[a10 * 32 + i] += c10 * xv; up[a11 * 32 + i] += c11 * xv;
            }
        }
    }
    __syncthreads();
    // convert fp32 -> bf16, folding 1/deg into the tap part (k<800)
    {
        int node = t >> 4, ks = (t & 15) * 52;
        float invd = 1.f / fmaxf((float)cnt2[nb + node], 1.f);
        const float* src = Ul + node * ULS + ks;
        unsigned short* dst = Ub + node * UBS + ks;
#pragma unroll 4
        for (int k = 0; k < 52; k++) {
            float v = src[k];
            if (ks + k < 800) v *= invd;
            dst[k] = f2bf(v);
        }
    }
    __syncthreads();
    // phase 2: MFMA. wave w -> o-tile w. D[node=quad*4+r][o=lane&15]
    int wv = t >> 6, lane = t & 63, quad = lane >> 4, lrow = lane & 15;
    f32x4 acc = {0.f, 0.f, 0.f, 0.f};
    const unsigned short* bbase = w2t + (wv * 16 + lrow) * KEXT;
    const unsigned short* abase = Ub + lrow * UBS;
#pragma unroll
    for (int kc = 0; kc < 26; kc++) {
        bf16x8 a = *(const bf16x8*)(abase + kc * 32 + quad * 8);
        bf16x8 b = *(const bf16x8*)(bbase + kc * 32 + quad * 8);
        acc = __builtin_amdgcn_mfma_f32_16x16x32_bf16(a, b, acc, 0, 0, 0);
    }
    int o = wv * 16 + lrow;
    float bo = b2[o];
#pragma unroll
    for (int r = 0; r < 4; r++) {
        int node = quad * 4 + r;
        float v = acc[r] + bo;
        v = v > 0.f ? v : expm1f(v);
        h2[(nb + node) * C2 + o] = v;
    }
}

// ---- pool2: view [19600,64] as [25,28,28,64] -> [25,14,14,64] == [100,3136] ----
__global__ void pool2(const float* __restrict__ h2, float* __restrict__ p2) {
    int idx = blockIdx.x * blockDim.x + threadIdx.x;
    if (idx >= 25 * 14 * 14 * C2) return;
    int o = idx & 63; int t = idx >> 6;
    int c = t % 14; int r = (t / 14) % 14; int b = t / 196;
    const float* base = h2 + (((b * 28 + 2 * r) * 28 + 2 * c) * C2 + o);
    float m = fmaxf(fmaxf(base[0], base[C2]),
                    fmaxf(base[28 * C2], base[28 * C2 + C2]));
    p2[idx] = m;
}

// ---- fc1 partials: grid (8 jt, 16 kz), block 256 (64 j x 4 bgroups of 25).
__global__ void fc1_part(const float* __restrict__ p2, const float* __restrict__ w,
                         float* __restrict__ z1p) {
    __shared__ float xs[100 * 196];  // 78.4 KB
    int t = threadIdx.x;
    int jt = blockIdx.x, kz = blockIdx.y;
    int j = (jt << 6) + (t & 63);
    int bg = t >> 6;                 // 0..3 -> rows bg*25..bg*25+24
    int k0 = kz * 196;
    for (int i = t; i < 100 * 196; i += 256) {
        int b = i / 196, kk = i - b * 196;
        xs[i] = p2[b * FC1_IN + k0 + kk];
    }
    __syncthreads();
    float acc[25];
#pragma unroll
    for (int b = 0; b < 25; b++) acc[b] = 0.f;
    const float* wp = w + j;
    for (int k = 0; k < 196; k += 4) {
        float w0 = wp[(k0 + k) * FC1_OUT];
        float w1 = wp[(k0 + k + 1) * FC1_OUT];
        float w2 = wp[(k0 + k + 2) * FC1_OUT];
        float w3 = wp[(k0 + k + 3) * FC1_OUT];
#pragma unroll
        for (int b = 0; b < 25; b++) {
            const float4 xv = *(const float4*)&xs[(bg * 25 + b) * 196 + k];
            acc[b] += xv.x * w0 + xv.y * w1 + xv.z * w2 + xv.w * w3;
        }
    }
#pragma unroll
    for (int b = 0; b < 25; b++)
        z1p[kz * (BSZ * FC1_OUT) + (bg * 25 + b) * FC1_OUT + j] = acc[b];
}

// ---- fc2 + log_softmax fused; sums 16 fc1 partials, applies fc1 bias+ELU ----
__global__ void fc2_lsm(const float* __restrict__ z1p, const float* __restrict__ fc1b,
                        const float* __restrict__ w, const float* __restrict__ fc2b,
                        float* __restrict__ out) {
    int b = blockIdx.x;
    int t = threadIdx.x;
    int wv = t >> 6;
    int lane = t & 63;
    float acc = 0.f;
#pragma unroll
    for (int m = 0; m < 8; m++) {
        int k = lane * 8 + m;
        float xv = fc1b[k];
        for (int kz = 0; kz < 16; kz++) xv += z1p[kz * (BSZ * FC1_OUT) + b * FC1_OUT + k];
        xv = xv > 0.f ? xv : expm1f(xv);
        acc += xv * w[k * 10 + wv];
    }
#pragma unroll
    for (int off = 32; off > 0; off >>= 1) acc += __shfl_down(acc, off);
    __shared__ float zs[10];
    if (lane == 0) {
        float z = acc + fc2b[wv];
        zs[wv] = z > 0.f ? z : expm1f(z);
    }
    __syncthreads();
    if (t < 10) {
        float m = -1e30f;
        for (int jj = 0; jj < 10; jj++) m = fmaxf(m, zs[jj]);
        float s = 0.f;
        for (int jj = 0; jj < 10; jj++) s += expf(zs[jj] - m);
        out[b * 10 + t] = zs[t] - m - logf(s);
    }
}

extern "C" void kernel_launch(void* const* d_in, const int* in_sizes, int n_in,
                              void* d_out, int out_size, void* d_ws, size_t ws_size,
                              hipStream_t stream) {
    const float* x     = (const float*)d_in[0];
    const float* ps0   = (const float*)d_in[1];
    const float* ps1   = (const float*)d_in[2];
    const float* W1    = (const float*)d_in[3];
    const float* root1 = (const float*)d_in[4];
    const float* b1    = (const float*)d_in[5];
    const float* W2    = (const float*)d_in[6];
    const float* root2 = (const float*)d_in[7];
    const float* b2v   = (const float*)d_in[8];
    const float* fc1w  = (const float*)d_in[9];
    const float* fc1b  = (const float*)d_in[10];
    const float* fc2w  = (const float*)d_in[11];
    const float* fc2b  = (const float*)d_in[12];
    const int*   ei0   = (const int*)d_in[13];
    const int*   ei1   = (const int*)d_in[14];

    float* ws = (float*)d_ws;
    int*   cnt1 = (int*)ws;                        //      78,400
    int*   cnt2 = (int*)(ws + 78400);              //      19,600
    // ---- memset boundary: 98,000 words ----
    int*   rec1 = (int*)(ws + 98000);              //   3,763,200 (N0*CAP)
    int*   rec2 = (int*)(ws + 3861200);            //     940,800 (N1*CAP)
    float* h1   = ws + 4802000;                    //   2,508,800
    float* p1   = ws + 7310800;                    //     627,200
    float* h2   = ws + 7938000;                    //   1,254,400
    float* p2   = ws + 9192400;                    //     313,600
    float* z1p  = ws + 9506000;                    //     819,200
    unsigned short* w2t = (unsigned short*)(ws + 10325200); // 53,248 ushorts (26,624 w)
    // high water: 10,351,824 words = 41.4 MB

    hipMemsetAsync(ws, 0, (size_t)98000 * sizeof(float), stream);

    bucket_edges<<<(E0 + 255) / 256, 256, 0, stream>>>(ei0, E0, cnt1, rec1);
    bucket_edges<<<(E1 + 255) / 256, 256, 0, stream>>>(ei1, E1, cnt2, rec2);
    w2t_prep<<<(64 * KEXT + 255) / 256, 256, 0, stream>>>(W2, root2, w2t);
    conv1_fused<<<N0 / 64, 256, 0, stream>>>(x, ps0, ei0, cnt1, rec1,
                                             W1, root1, b1, h1);
    pool1<<<(N1 * C1 + 255) / 256, 256, 0, stream>>>(h1, p1);
    conv2_fused<<<N1 / 16, 256, 0, stream>>>(p1, ps1, ei1, cnt2, rec2,
                                             w2t, b2v, h2);
    pool2<<<(25 * 14 * 14 * C2 + 255) / 256, 256, 0, stream>>>(h2, p2);
    fc1_part<<<dim3(8, 16), 256, 0, stream>>>(p2, fc1w, z1p);
    fc2_lsm<<<BSZ, 640, 0, stream>>>(z1p, fc1b, fc2w, fc2b, (float*)d_out);
}

// Round 9
// 310.918 us; speedup vs baseline: 1.8440x; 1.0426x over previous
//
#include <hip/hip_runtime.h>
#include <hip/hip_bf16.h>

#define KK 5
constexpr int N0 = 78400;     // B*28*28
constexpr int E0 = 627200;    // N0*8
constexpr int N1 = 19600;     // B*14*14
constexpr int E1 = 156800;    // N1*8
constexpr int C1 = 32, C2 = 64;
constexpr int BSZ = 100;
constexpr int FC1_IN = 3136, FC1_OUT = 512;
constexpr int CAP = 48;       // max stored edges per node (Poisson(8) tail ~1e-20)
constexpr int KEXT = 832;     // 800 tap-space + 32 root channels
constexpr int ULS = 836;      // LDS fp32 U row stride: %4==0 (16B align), %32==4 (bank stagger)

typedef __attribute__((ext_vector_type(8))) short bf16x8;
typedef __attribute__((ext_vector_type(4))) float f32x4;

__device__ __forceinline__ unsigned short f2bf(float f) {
    union { float f; unsigned u; } v; v.f = f;
    unsigned u = v.u;
    unsigned r = (u + 0x7FFF + ((u >> 16) & 1)) >> 16;   // RNE
    return (unsigned short)r;
}

__device__ __forceinline__ void taps_of(const float* pseudo, int e,
                                        int& a00, int& a01, int& a10, int& a11,
                                        float& c00, float& c01, float& c10, float& c11) {
    float px = pseudo[2 * e] * (KK - 1);
    float py = pseudo[2 * e + 1] * (KK - 1);
    float kfx = floorf(px), kfy = floorf(py);
    float fx = px - kfx, fy = py - kfy;
    int k0x = min(max((int)kfx, 0), KK - 1);
    int k0y = min(max((int)kfy, 0), KK - 1);
    int k1x = min(k0x + 1, KK - 1), k1y = min(k0y + 1, KK - 1);
    a00 = k0x * KK + k0y; a01 = k0x * KK + k1y;
    a10 = k1x * KK + k0y; a11 = k1x * KK + k1y;
    float gx = 1.f - fx, gy = 1.f - fy;
    c00 = gx * gy; c01 = gx * fy; c10 = fx * gy; c11 = fx * fy;
}

// ---- bucket: one int atomic per edge; store edge id in dst's slot list ----
__global__ void bucket_edges(const int* __restrict__ ei, int nedges,
                             int* __restrict__ cnt, int* __restrict__ rec) {
    int e = blockIdx.x * blockDim.x + threadIdx.x;
    if (e >= nedges) return;
    int dstn = ei[nedges + e];
    int r = atomicAdd(&cnt[dstn], 1);
    if (r < CAP) rec[dstn * CAP + r] = e;
}

// ---- conv1 fused: 64 nodes/block. Phase1: tap-space S in LDS (4 thr/node).
//      Phase2: h1[n,o] = ELU((S@W1)/deg + x*root + bias). No atomics. ----
__global__ void conv1_fused(const float* __restrict__ x, const float* __restrict__ ps0,
                            const int* __restrict__ ei0, const int* __restrict__ cnt1,
                            const int* __restrict__ rec1, const float* __restrict__ W1,
                            const float* __restrict__ root, const float* __restrict__ bias,
                            float* __restrict__ h1) {
    __shared__ float S4[64][4][25];   // 25.6 KB, thread-private quadrants
    __shared__ float Sr[64][25];      // 6.4 KB, reduced
    int t = threadIdx.x;
    int nb = blockIdx.x * 64;
    {
        int q = t & 3, nl = t >> 2;
        float* sp = &S4[nl][q][0];
#pragma unroll
        for (int a = 0; a < 25; a++) sp[a] = 0.f;
        int m = min(cnt1[nb + nl], CAP);
        const int* rp = rec1 + (nb + nl) * CAP;
        for (int r = q; r < m; r += 4) {
            int e = rp[r];
            int srcn = ei0[e];
            int a00, a01, a10, a11; float c00, c01, c10, c11;
            taps_of(ps0, e, a00, a01, a10, a11, c00, c01, c10, c11);
            float xv = x[srcn];
            sp[a00] += c00 * xv; sp[a01] += c01 * xv;
            sp[a10] += c10 * xv; sp[a11] += c11 * xv;
        }
    }
    __syncthreads();
    for (int idx = t; idx < 64 * 25; idx += 256) {
        int nl = idx / 25, a = idx - nl * 25;
        Sr[nl][a] = S4[nl][0][a] + S4[nl][1][a] + S4[nl][2][a] + S4[nl][3][a];
    }
    __syncthreads();
    int o = t & 31, ng = t >> 5;
    float w1c[25];
#pragma unroll
    for (int a = 0; a < 25; a++) w1c[a] = W1[a * C1 + o];
    float ro = root[o], bo = bias[o];
    for (int j = 0; j < 8; j++) {
        int nl = ng * 8 + j;
        int n = nb + nl;
        float acc = 0.f;
#pragma unroll
        for (int a = 0; a < 25; a++) acc += Sr[nl][a] * w1c[a];
        float v = acc / fmaxf((float)cnt1[n], 1.f) + x[n] * ro + bo;
        h1[n * C1 + o] = v > 0.f ? v : expm1f(v);
    }
}

// ---- pool1: [100,28,28,32] -> [100,14,14,32] ----
__global__ void pool1(const float* __restrict__ h1, float* __restrict__ p1) {
    int idx = blockIdx.x * blockDim.x + threadIdx.x;
    if (idx >= N1 * C1) return;
    int o = idx & 31; int t = idx >> 5;
    int c = t % 14; int r = (t / 14) % 14; int b = t / 196;
    const float* base = h1 + (((b * 28 + 2 * r) * 28 + 2 * c) * C1 + o);
    float m = fmaxf(fmaxf(base[0], base[C1]),
                    fmaxf(base[28 * C1], base[28 * C1 + C1]));
    p1[idx] = m;
}

// ---- w2t prep: bf16 transposed W2ext [64 o][832 k]; k<800 -> W2, else root2 ----
__global__ void w2t_prep(const float* __restrict__ W2, const float* __restrict__ root2,
                         unsigned short* __restrict__ w2t) {
    int idx = blockIdx.x * blockDim.x + threadIdx.x;
    if (idx >= 64 * KEXT) return;
    int o = idx / KEXT, k = idx - o * KEXT;
    float v = (k < 800) ? W2[k * 64 + o] : root2[(k - 800) * 64 + o];
    w2t[idx] = f2bf(v);
}

// ---- conv2 fused (MFMA): 16 nodes/block, LDS 53.5 KB -> 3 blocks/CU.
//  Phase1: U[16][832] fp32 in LDS; 1/deg folded into tap coefficients.
//  Phase2: on-the-fly fp32->bf16 pack of the A-fragment, then
//          h2 = ELU( U_bf16 @ w2t^T + b2 ) via mfma_f32_16x16x32_bf16.
__global__ void conv2_fused(const float* __restrict__ p1, const float* __restrict__ ps1,
                            const int* __restrict__ ei1, const int* __restrict__ cnt2,
                            const int* __restrict__ rec2,
                            const unsigned short* __restrict__ w2t,
                            const float* __restrict__ b2, float* __restrict__ h2) {
    __shared__ float Ul[16 * ULS];          // 53.5 KB
    int t = threadIdx.x;
    int nb = blockIdx.x * 16;
    // phase 1: edge gather into fp32 tap-space, invd pre-folded (taps only)
    {
        int i = t & 31, nl = t >> 5;
        for (int nn = nl; nn < 16; nn += 8) {
            int n = nb + nn;
            float* up = Ul + nn * ULS;
#pragma unroll
            for (int a = 0; a < 25; a++) up[a * 32 + i] = 0.f;
            up[800 + i] = p1[n * C1 + i];    // root channels, unscaled
            int cnt = cnt2[n];
            int m = min(cnt, CAP);
            float invd = 1.f / fmaxf((float)cnt, 1.f);
            const int* rp = rec2 + n * CAP;
            for (int r = 0; r < m; r++) {
                int e = rp[r];
                int srcn = ei1[e];
                int a00, a01, a10, a11; float c00, c01, c10, c11;
                taps_of(ps1, e, a00, a01, a10, a11, c00, c01, c10, c11);
                float xv = p1[srcn * C1 + i] * invd;
                up[a00 * 32 + i] += c00 * xv; up[a01 * 32 + i] += c01 * xv;
                up[a10 * 32 + i] += c10 * xv; up[a11 * 32 + i] += c11 * xv;
            }
        }
    }
    __syncthreads();
    // phase 2: MFMA. wave w -> o-tile w. D[node=quad*4+r][o=lane&15]
    int wv = t >> 6, lane = t & 63, quad = lane >> 4, lrow = lane & 15;
    f32x4 acc = {0.f, 0.f, 0.f, 0.f};
    const unsigned short* bbase = w2t + (wv * 16 + lrow) * KEXT;
    const float* abase = Ul + lrow * ULS;
#pragma unroll
    for (int kc = 0; kc < 26; kc++) {
        float4 a0 = *(const float4*)(abase + kc * 32 + quad * 8);
        float4 a1 = *(const float4*)(abase + kc * 32 + quad * 8 + 4);
        bf16x8 a;
        a[0] = (short)f2bf(a0.x); a[1] = (short)f2bf(a0.y);
        a[2] = (short)f2bf(a0.z); a[3] = (short)f2bf(a0.w);
        a[4] = (short)f2bf(a1.x); a[5] = (short)f2bf(a1.y);
        a[6] = (short)f2bf(a1.z); a[7] = (short)f2bf(a1.w);
        bf16x8 b = *(const bf16x8*)(bbase + kc * 32 + quad * 8);
        acc = __builtin_amdgcn_mfma_f32_16x16x32_bf16(a, b, acc, 0, 0, 0);
    }
    int o = wv * 16 + lrow;
    float bo = b2[o];
#pragma unroll
    for (int r = 0; r < 4; r++) {
        int node = quad * 4 + r;
        float v = acc[r] + bo;
        v = v > 0.f ? v : expm1f(v);
        h2[(nb + node) * C2 + o] = v;
    }
}

// ---- pool2: view [19600,64] as [25,28,28,64] -> [25,14,14,64] == [100,3136] ----
__global__ void pool2(const float* __restrict__ h2, float* __restrict__ p2) {
    int idx = blockIdx.x * blockDim.x + threadIdx.x;
    if (idx >= 25 * 14 * 14 * C2) return;
    int o = idx & 63; int t = idx >> 6;
    int c = t % 14; int r = (t / 14) % 14; int b = t / 196;
    const float* base = h2 + (((b * 28 + 2 * r) * 28 + 2 * c) * C2 + o);
    float m = fmaxf(fmaxf(base[0], base[C2]),
                    fmaxf(base[28 * C2], base[28 * C2 + C2]));
    p2[idx] = m;
}

// ---- fc1 partials: grid (8 jt, 16 kz), block 256 (64 j x 4 bgroups of 25).
__global__ void fc1_part(const float* __restrict__ p2, const float* __restrict__ w,
                         float* __restrict__ z1p) {
    __shared__ float xs[100 * 196];  // 78.4 KB
    int t = threadIdx.x;
    int jt = blockIdx.x, kz = blockIdx.y;
    int j = (jt << 6) + (t & 63);
    int bg = t >> 6;                 // 0..3 -> rows bg*25..bg*25+24
    int k0 = kz * 196;
    for (int i = t; i < 100 * 196; i += 256) {
        int b = i / 196, kk = i - b * 196;
        xs[i] = p2[b * FC1_IN + k0 + kk];
    }
    __syncthreads();
    float acc[25];
#pragma unroll
    for (int b = 0; b < 25; b++) acc[b] = 0.f;
    const float* wp = w + j;
    for (int k = 0; k < 196; k += 4) {
        float w0 = wp[(k0 + k) * FC1_OUT];
        float w1 = wp[(k0 + k + 1) * FC1_OUT];
        float w2 = wp[(k0 + k + 2) * FC1_OUT];
        float w3 = wp[(k0 + k + 3) * FC1_OUT];
#pragma unroll
        for (int b = 0; b < 25; b++) {
            const float4 xv = *(const float4*)&xs[(bg * 25 + b) * 196 + k];
            acc[b] += xv.x * w0 + xv.y * w1 + xv.z * w2 + xv.w * w3;
        }
    }
#pragma unroll
    for (int b = 0; b < 25; b++)
        z1p[kz * (BSZ * FC1_OUT) + (bg * 25 + b) * FC1_OUT + j] = acc[b];
}

// ---- fc2 + log_softmax fused; sums 16 fc1 partials, applies fc1 bias+ELU ----
__global__ void fc2_lsm(const float* __restrict__ z1p, const float* __restrict__ fc1b,
                        const float* __restrict__ w, const float* __restrict__ fc2b,
                        float* __restrict__ out) {
    int b = blockIdx.x;
    int t = threadIdx.x;
    int wv = t >> 6;
    int lane = t & 63;
    float acc = 0.f;
#pragma unroll
    for (int m = 0; m < 8; m++) {
        int k = lane * 8 + m;
        float xv = fc1b[k];
        for (int kz = 0; kz < 16; kz++) xv += z1p[kz * (BSZ * FC1_OUT) + b * FC1_OUT + k];
        xv = xv > 0.f ? xv : expm1f(xv);
        acc += xv * w[k * 10 + wv];
    }
#pragma unroll
    for (int off = 32; off > 0; off >>= 1) acc += __shfl_down(acc, off);
    __shared__ float zs[10];
    if (lane == 0) {
        float z = acc + fc2b[wv];
        zs[wv] = z > 0.f ? z : expm1f(z);
    }
    __syncthreads();
    if (t < 10) {
        float m = -1e30f;
        for (int jj = 0; jj < 10; jj++) m = fmaxf(m, zs[jj]);
        float s = 0.f;
        for (int jj = 0; jj < 10; jj++) s += expf(zs[jj] - m);
        out[b * 10 + t] = zs[t] - m - logf(s);
    }
}

extern "C" void kernel_launch(void* const* d_in, const int* in_sizes, int n_in,
                              void* d_out, int out_size, void* d_ws, size_t ws_size,
                              hipStream_t stream) {
    const float* x     = (const float*)d_in[0];
    const float* ps0   = (const float*)d_in[1];
    const float* ps1   = (const float*)d_in[2];
    const float* W1    = (const float*)d_in[3];
    const float* root1 = (const float*)d_in[4];
    const float* b1    = (const float*)d_in[5];
    const float* W2    = (const float*)d_in[6];
    const float* root2 = (const float*)d_in[7];
    const float* b2v   = (const float*)d_in[8];
    const float* fc1w  = (const float*)d_in[9];
    const float* fc1b  = (const float*)d_in[10];
    const float* fc2w  = (const float*)d_in[11];
    const float* fc2b  = (const float*)d_in[12];
    const int*   ei0   = (const int*)d_in[13];
    const int*   ei1   = (const int*)d_in[14];

    float* ws = (float*)d_ws;
    int*   cnt1 = (int*)ws;                        //      78,400
    int*   cnt2 = (int*)(ws + 78400);              //      19,600
    // ---- memset boundary: 98,000 words ----
    int*   rec1 = (int*)(ws + 98000);              //   3,763,200 (N0*CAP)
    int*   rec2 = (int*)(ws + 3861200);            //     940,800 (N1*CAP)
    float* h1   = ws + 4802000;                    //   2,508,800
    float* p1   = ws + 7310800;                    //     627,200
    float* h2   = ws + 7938000;                    //   1,254,400
    float* p2   = ws + 9192400;                    //     313,600
    float* z1p  = ws + 9506000;                    //     819,200
    unsigned short* w2t = (unsigned short*)(ws + 10325200); // 53,248 ushorts (26,624 w)
    // high water: 10,351,824 words = 41.4 MB

    hipMemsetAsync(ws, 0, (size_t)98000 * sizeof(float), stream);

    bucket_edges<<<(E0 + 255) / 256, 256, 0, stream>>>(ei0, E0, cnt1, rec1);
    bucket_edges<<<(E1 + 255) / 256, 256, 0, stream>>>(ei1, E1, cnt2, rec2);
    w2t_prep<<<(64 * KEXT + 255) / 256, 256, 0, stream>>>(W2, root2, w2t);
    conv1_fused<<<N0 / 64, 256, 0, stream>>>(x, ps0, ei0, cnt1, rec1,
                                             W1, root1, b1, h1);
    pool1<<<(N1 * C1 + 255) / 256, 256, 0, stream>>>(h1, p1);
    conv2_fused<<<N1 / 16, 256, 0, stream>>>(p1, ps1, ei1, cnt2, rec2,
                                             w2t, b2v, h2);
    pool2<<<(25 * 14 * 14 * C2 + 255) / 256, 256, 0, stream>>>(h2, p2);
    fc1_part<<<dim3(8, 16), 256, 0, stream>>>(p2, fc1w, z1p);
    fc2_lsm<<<BSZ, 640, 0, stream>>>(z1p, fc1b, fc2w, fc2b, (float*)d_out);
}

// Round 10
// 248.346 us; speedup vs baseline: 2.3086x; 1.2520x over previous
//
#include <hip/hip_runtime.h>
#include <hip/hip_bf16.h>

#define KK 5
constexpr int N0 = 78400;     // B*28*28
constexpr int E0 = 627200;    // N0*8
constexpr int N1 = 19600;     // B*14*14
constexpr int E1 = 156800;    // N1*8
constexpr int C1 = 32, C2 = 64;
constexpr int BSZ = 100;
constexpr int FC1_IN = 3136, FC1_OUT = 512;
constexpr int CAP = 48;       // max stored edges per node (Poisson(8) tail ~1e-20)
constexpr int KEXT = 832;     // 800 tap-space + 32 root channels
constexpr int ULS = 836;      // LDS fp32 U row stride: %4==0 (16B align), %32==4 (bank stagger)

typedef __attribute__((ext_vector_type(8))) short bf16x8;
typedef __attribute__((ext_vector_type(4))) float f32x4;

__device__ __forceinline__ unsigned short f2bf(float f) {
    union { float f; unsigned u; } v; v.f = f;
    unsigned u = v.u;
    unsigned r = (u + 0x7FFF + ((u >> 16) & 1)) >> 16;   // RNE
    return (unsigned short)r;
}

__device__ __forceinline__ void taps_of(const float* pseudo, int e,
                                        int& a00, int& a01, int& a10, int& a11,
                                        float& c00, float& c01, float& c10, float& c11) {
    float px = pseudo[2 * e] * (KK - 1);
    float py = pseudo[2 * e + 1] * (KK - 1);
    float kfx = floorf(px), kfy = floorf(py);
    float fx = px - kfx, fy = py - kfy;
    int k0x = min(max((int)kfx, 0), KK - 1);
    int k0y = min(max((int)kfy, 0), KK - 1);
    int k1x = min(k0x + 1, KK - 1), k1y = min(k0y + 1, KK - 1);
    a00 = k0x * KK + k0y; a01 = k0x * KK + k1y;
    a10 = k1x * KK + k0y; a11 = k1x * KK + k1y;
    float gx = 1.f - fx, gy = 1.f - fy;
    c00 = gx * gy; c01 = gx * fy; c10 = fx * gy; c11 = fx * fy;
}

// ---- bucket: one int atomic per edge; store edge id in dst's slot list ----
__global__ void bucket_edges(const int* __restrict__ ei, int nedges,
                             int* __restrict__ cnt, int* __restrict__ rec) {
    int e = blockIdx.x * blockDim.x + threadIdx.x;
    if (e >= nedges) return;
    int dstn = ei[nedges + e];
    int r = atomicAdd(&cnt[dstn], 1);
    if (r < CAP) rec[dstn * CAP + r] = e;
}

// ---- conv1 fused: 64 nodes/block. Phase1: tap-space S in LDS (4 thr/node).
//      Phase2: h1[n,o] = ELU((S@W1)/deg + x*root + bias). No atomics. ----
__global__ void conv1_fused(const float* __restrict__ x, const float* __restrict__ ps0,
                            const int* __restrict__ ei0, const int* __restrict__ cnt1,
                            const int* __restrict__ rec1, const float* __restrict__ W1,
                            const float* __restrict__ root, const float* __restrict__ bias,
                            float* __restrict__ h1) {
    __shared__ float S4[64][4][25];   // 25.6 KB, thread-private quadrants
    __shared__ float Sr[64][25];      // 6.4 KB, reduced
    int t = threadIdx.x;
    int nb = blockIdx.x * 64;
    {
        int q = t & 3, nl = t >> 2;
        float* sp = &S4[nl][q][0];
#pragma unroll
        for (int a = 0; a < 25; a++) sp[a] = 0.f;
        int m = min(cnt1[nb + nl], CAP);
        const int* rp = rec1 + (nb + nl) * CAP;
        for (int r = q; r < m; r += 4) {
            int e = rp[r];
            int srcn = ei0[e];
            int a00, a01, a10, a11; float c00, c01, c10, c11;
            taps_of(ps0, e, a00, a01, a10, a11, c00, c01, c10, c11);
            float xv = x[srcn];
            sp[a00] += c00 * xv; sp[a01] += c01 * xv;
            sp[a10] += c10 * xv; sp[a11] += c11 * xv;
        }
    }
    __syncthreads();
    for (int idx = t; idx < 64 * 25; idx += 256) {
        int nl = idx / 25, a = idx - nl * 25;
        Sr[nl][a] = S4[nl][0][a] + S4[nl][1][a] + S4[nl][2][a] + S4[nl][3][a];
    }
    __syncthreads();
    int o = t & 31, ng = t >> 5;
    float w1c[25];
#pragma unroll
    for (int a = 0; a < 25; a++) w1c[a] = W1[a * C1 + o];
    float ro = root[o], bo = bias[o];
    for (int j = 0; j < 8; j++) {
        int nl = ng * 8 + j;
        int n = nb + nl;
        float acc = 0.f;
#pragma unroll
        for (int a = 0; a < 25; a++) acc += Sr[nl][a] * w1c[a];
        float v = acc / fmaxf((float)cnt1[n], 1.f) + x[n] * ro + bo;
        h1[n * C1 + o] = v > 0.f ? v : expm1f(v);
    }
}

// ---- pool1: [100,28,28,32] -> [100,14,14,32] ----
__global__ void pool1(const float* __restrict__ h1, float* __restrict__ p1) {
    int idx = blockIdx.x * blockDim.x + threadIdx.x;
    if (idx >= N1 * C1) return;
    int o = idx & 31; int t = idx >> 5;
    int c = t % 14; int r = (t / 14) % 14; int b = t / 196;
    const float* base = h1 + (((b * 28 + 2 * r) * 28 + 2 * c) * C1 + o);
    float m = fmaxf(fmaxf(base[0], base[C1]),
                    fmaxf(base[28 * C1], base[28 * C1 + C1]));
    p1[idx] = m;
}

// ---- w2t prep: bf16 transposed W2ext [64 o][832 k]; k<800 -> W2, else root2 ----
__global__ void w2t_prep(const float* __restrict__ W2, const float* __restrict__ root2,
                         unsigned short* __restrict__ w2t) {
    int idx = blockIdx.x * blockDim.x + threadIdx.x;
    if (idx >= 64 * KEXT) return;
    int o = idx / KEXT, k = idx - o * KEXT;
    float v = (k < 800) ? W2[k * 64 + o] : root2[(k - 800) * 64 + o];
    w2t[idx] = f2bf(v);
}

// ---- wt1 prep: fc1w [3136,512] fp32 -> transposed bf16 wt1[512][3136] ----
__global__ void wt1_prep(const float* __restrict__ w, unsigned short* __restrict__ wt1) {
    __shared__ unsigned short tile[64 * 66];
    int t = threadIdx.x;
    int k0 = blockIdx.x * 64, j0 = blockIdx.y * 64;
    int jj = t & 63, ks = t >> 6;
    for (int kk = ks; kk < 64; kk += 4)
        tile[kk * 66 + jj] = f2bf(w[(k0 + kk) * FC1_OUT + j0 + jj]);
    __syncthreads();
    int kk = t & 63, js = t >> 6;
    for (int j2 = js; j2 < 64; j2 += 4)
        wt1[(j0 + j2) * FC1_IN + k0 + kk] = tile[kk * 66 + j2];
}

// ---- conv2 fused (MFMA): 16 nodes/block, LDS 53.5 KB -> 3 blocks/CU.
__global__ void conv2_fused(const float* __restrict__ p1, const float* __restrict__ ps1,
                            const int* __restrict__ ei1, const int* __restrict__ cnt2,
                            const int* __restrict__ rec2,
                            const unsigned short* __restrict__ w2t,
                            const float* __restrict__ b2, float* __restrict__ h2) {
    __shared__ float Ul[16 * ULS];          // 53.5 KB
    int t = threadIdx.x;
    int nb = blockIdx.x * 16;
    {
        int i = t & 31, nl = t >> 5;
        for (int nn = nl; nn < 16; nn += 8) {
            int n = nb + nn;
            float* up = Ul + nn * ULS;
#pragma unroll
            for (int a = 0; a < 25; a++) up[a * 32 + i] = 0.f;
            up[800 + i] = p1[n * C1 + i];    // root channels, unscaled
            int cnt = cnt2[n];
            int m = min(cnt, CAP);
            float invd = 1.f / fmaxf((float)cnt, 1.f);
            const int* rp = rec2 + n * CAP;
            for (int r = 0; r < m; r++) {
                int e = rp[r];
                int srcn = ei1[e];
                int a00, a01, a10, a11; float c00, c01, c10, c11;
                taps_of(ps1, e, a00, a01, a10, a11, c00, c01, c10, c11);
                float xv = p1[srcn * C1 + i] * invd;
                up[a00 * 32 + i] += c00 * xv; up[a01 * 32 + i] += c01 * xv;
                up[a10 * 32 + i] += c10 * xv; up[a11 * 32 + i] += c11 * xv;
            }
        }
    }
    __syncthreads();
    int wv = t >> 6, lane = t & 63, quad = lane >> 4, lrow = lane & 15;
    f32x4 acc = {0.f, 0.f, 0.f, 0.f};
    const unsigned short* bbase = w2t + (wv * 16 + lrow) * KEXT;
    const float* abase = Ul + lrow * ULS;
#pragma unroll
    for (int kc = 0; kc < 26; kc++) {
        float4 a0 = *(const float4*)(abase + kc * 32 + quad * 8);
        float4 a1 = *(const float4*)(abase + kc * 32 + quad * 8 + 4);
        bf16x8 a;
        a[0] = (short)f2bf(a0.x); a[1] = (short)f2bf(a0.y);
        a[2] = (short)f2bf(a0.z); a[3] = (short)f2bf(a0.w);
        a[4] = (short)f2bf(a1.x); a[5] = (short)f2bf(a1.y);
        a[6] = (short)f2bf(a1.z); a[7] = (short)f2bf(a1.w);
        bf16x8 b = *(const bf16x8*)(bbase + kc * 32 + quad * 8);
        acc = __builtin_amdgcn_mfma_f32_16x16x32_bf16(a, b, acc, 0, 0, 0);
    }
    int o = wv * 16 + lrow;
    float bo = b2[o];
#pragma unroll
    for (int r = 0; r < 4; r++) {
        int node = quad * 4 + r;
        float v = acc[r] + bo;
        v = v > 0.f ? v : expm1f(v);
        h2[(nb + node) * C2 + o] = v;
    }
}

// ---- pool2 -> bf16 [112 x 3136], rows 100..111 zeroed (M-pad for MFMA) ----
__global__ void pool2b(const float* __restrict__ h2, unsigned short* __restrict__ p2b) {
    int idx = blockIdx.x * blockDim.x + threadIdx.x;
    if (idx >= 112 * FC1_IN) return;
    if (idx >= 100 * FC1_IN) { p2b[idx] = 0; return; }
    int o = idx & 63; int t2 = idx >> 6;
    int c = t2 % 14; int r = (t2 / 14) % 14; int b = t2 / 196;
    const float* base = h2 + (((b * 28 + 2 * r) * 28 + 2 * c) * C2 + o);
    float m = fmaxf(fmaxf(base[0], base[C2]),
                    fmaxf(base[28 * C2], base[28 * C2 + C2]));
    p2b[idx] = f2bf(m);
}

// ---- fc1 MFMA: [112,3136]bf16 @ wt1^T -> z1p fp32 partials (2 kz).
// grid (8 jt, 7 mt, 2 kz), block 256. Wave = 16x16 out tile, 49 MFMA. ----
__global__ void gemm_fc1(const unsigned short* __restrict__ p2b,
                         const unsigned short* __restrict__ wt1,
                         float* __restrict__ z1p) {
    constexpr int AS = 232;              // 224 + 8 pad, 16B aligned
    __shared__ unsigned short as_[16 * AS];   // 7.4 KB
    int t = threadIdx.x;
    int jt = blockIdx.x, mt = blockIdx.y, kz = blockIdx.z;
    int wv = t >> 6, lane = t & 63, quad = lane >> 4, lrow = lane & 15;
    int m0 = mt * 16;
    int kbase = kz * 1568;
    const unsigned short* bbase = wt1 + (jt * 64 + wv * 16 + lrow) * FC1_IN + kbase;
    f32x4 acc = {0.f, 0.f, 0.f, 0.f};
    for (int ch = 0; ch < 7; ch++) {
        __syncthreads();
        for (int slot = t; slot < 448; slot += 256) {   // 16 rows x 28 uint4
            int r = slot / 28, c = slot - (slot / 28) * 28;
            *(uint4*)(as_ + r * AS + c * 8) =
                *(const uint4*)(p2b + (m0 + r) * FC1_IN + kbase + ch * 224 + c * 8);
        }
        __syncthreads();
        const unsigned short* ab = as_ + lrow * AS;
        const unsigned short* bb = bbase + ch * 224;
#pragma unroll
        for (int kk = 0; kk < 7; kk++) {
            bf16x8 a = *(const bf16x8*)(ab + kk * 32 + quad * 8);
            bf16x8 b = *(const bf16x8*)(bb + kk * 32 + quad * 8);
            acc = __builtin_amdgcn_mfma_f32_16x16x32_bf16(a, b, acc, 0, 0, 0);
        }
    }
    int n = jt * 64 + wv * 16 + lrow;
#pragma unroll
    for (int r = 0; r < 4; r++) {
        int m = m0 + quad * 4 + r;
        z1p[kz * (112 * FC1_OUT) + m * FC1_OUT + n] = acc[r];
    }
}

// ---- fc2 + log_softmax fused; sums 2 fc1 partials, applies fc1 bias+ELU ----
__global__ void fc2_lsm(const float* __restrict__ z1p, const float* __restrict__ fc1b,
                        const float* __restrict__ w, const float* __restrict__ fc2b,
                        float* __restrict__ out) {
    int b = blockIdx.x;
    int t = threadIdx.x;
    int wv = t >> 6;
    int lane = t & 63;
    float acc = 0.f;
#pragma unroll
    for (int m = 0; m < 8; m++) {
        int k = lane * 8 + m;
        float xv = fc1b[k] + z1p[b * FC1_OUT + k] + z1p[112 * FC1_OUT + b * FC1_OUT + k];
        xv = xv > 0.f ? xv : expm1f(xv);
        acc += xv * w[k * 10 + wv];
    }
#pragma unroll
    for (int off = 32; off > 0; off >>= 1) acc += __shfl_down(acc, off);
    __shared__ float zs[10];
    if (lane == 0) {
        float z = acc + fc2b[wv];
        zs[wv] = z > 0.f ? z : expm1f(z);
    }
    __syncthreads();
    if (t < 10) {
        float m = -1e30f;
        for (int jj = 0; jj < 10; jj++) m = fmaxf(m, zs[jj]);
        float s = 0.f;
        for (int jj = 0; jj < 10; jj++) s += expf(zs[jj] - m);
        out[b * 10 + t] = zs[t] - m - logf(s);
    }
}

extern "C" void kernel_launch(void* const* d_in, const int* in_sizes, int n_in,
                              void* d_out, int out_size, void* d_ws, size_t ws_size,
                              hipStream_t stream) {
    const float* x     = (const float*)d_in[0];
    const float* ps0   = (const float*)d_in[1];
    const float* ps1   = (const float*)d_in[2];
    const float* W1    = (const float*)d_in[3];
    const float* root1 = (const float*)d_in[4];
    const float* b1    = (const float*)d_in[5];
    const float* W2    = (const float*)d_in[6];
    const float* root2 = (const float*)d_in[7];
    const float* b2v   = (const float*)d_in[8];
    const float* fc1w  = (const float*)d_in[9];
    const float* fc1b  = (const float*)d_in[10];
    const float* fc2w  = (const float*)d_in[11];
    const float* fc2b  = (const float*)d_in[12];
    const int*   ei0   = (const int*)d_in[13];
    const int*   ei1   = (const int*)d_in[14];

    float* ws = (float*)d_ws;
    int*   cnt1 = (int*)ws;                        //      78,400
    int*   cnt2 = (int*)(ws + 78400);              //      19,600
    // ---- memset boundary: 98,000 words ----
    int*   rec1 = (int*)(ws + 98000);              //   3,763,200 (N0*CAP)
    int*   rec2 = (int*)(ws + 3861200);            //     940,800 (N1*CAP)
    float* h1   = ws + 4802000;                    //   2,508,800
    float* p1   = ws + 7310800;                    //     627,200
    float* h2   = ws + 7938000;                    //   1,254,400
    unsigned short* p2b = (unsigned short*)(ws + 9192400);  // 351,232 us = 175,616 w
    float* z1p  = ws + 9368016;                    //     114,688 (2 x 112 x 512)
    unsigned short* w2t = (unsigned short*)(ws + 9482704);  // 53,248 us = 26,624 w
    unsigned short* wt1 = (unsigned short*)(ws + 9509328);  // 1,605,632 us = 802,816 w
    // high water: 10,312,144 words = 41.2 MB

    hipMemsetAsync(ws, 0, (size_t)98000 * sizeof(float), stream);

    bucket_edges<<<(E0 + 255) / 256, 256, 0, stream>>>(ei0, E0, cnt1, rec1);
    bucket_edges<<<(E1 + 255) / 256, 256, 0, stream>>>(ei1, E1, cnt2, rec2);
    w2t_prep<<<(64 * KEXT + 255) / 256, 256, 0, stream>>>(W2, root2, w2t);
    wt1_prep<<<dim3(49, 8), 256, 0, stream>>>(fc1w, wt1);
    conv1_fused<<<N0 / 64, 256, 0, stream>>>(x, ps0, ei0, cnt1, rec1,
                                             W1, root1, b1, h1);
    pool1<<<(N1 * C1 + 255) / 256, 256, 0, stream>>>(h1, p1);
    conv2_fused<<<N1 / 16, 256, 0, stream>>>(p1, ps1, ei1, cnt2, rec2,
                                             w2t, b2v, h2);
    pool2b<<<(112 * FC1_IN + 255) / 256, 256, 0, stream>>>(h2, p2b);
    gemm_fc1<<<dim3(8, 7, 2), 256, 0, stream>>>(p2b, wt1, z1p);
    fc2_lsm<<<BSZ, 640, 0, stream>>>(z1p, fc1b, fc2w, fc2b, (float*)d_out);
}